// Round 10
// baseline (267.355 us; speedup 1.0000x reference)
//
#include <hip/hip_runtime.h>

typedef __bf16 bf16;
typedef bf16 bf16x8 __attribute__((ext_vector_type(8)));
typedef float f32x4 __attribute__((ext_vector_type(4)));
typedef unsigned short ushort;
typedef ushort ushort4v __attribute__((ext_vector_type(4)));

#define BB 8192   // batch
#define NN 2048   // nodes

// ---------------------------------------------------------------------------
__device__ __forceinline__ void async16(const void* g, void* l) {
    __builtin_amdgcn_global_load_lds(
        (__attribute__((address_space(1))) void*)(void*)g,
        (__attribute__((address_space(3))) void*)l,
        16, 0, 0);
}

// ---------------------------------------------------------------------------
// K1 v5 (unchanged): gather-conv writing the TRANSPOSED batch-8-grouped
// layout V'[g][p][e] = conv(batch g*8+e, node p).
// A[m][k0..k0+8) = V'[(m&3)*256 + k0/8][m>>2][0..8) -> 16B-contiguous chunks.
// Blocks >= 1024 do the lin_w f32->bf16 convert.
__global__ __launch_bounds__(256) void conv_gather_t(
    const float* __restrict__ x, const float* __restrict__ label,
    const int* __restrict__ adj, const float* __restrict__ cw,
    const float* __restrict__ cb, bf16* __restrict__ Vp,
    const float* __restrict__ W, bf16* __restrict__ Wb) {
    const int blk = blockIdx.x;
    const int t   = threadIdx.x;

    if (blk >= 1024) {
        const size_t f4 = ((size_t)(blk - 1024) * 256 + t) * 4;
        const float4* Wf = (const float4*)W;
        float4 v0 = Wf[f4 + 0], v1 = Wf[f4 + 1];
        float4 v2 = Wf[f4 + 2], v3 = Wf[f4 + 3];
        bf16x8 o0, o1;
        o0[0]=(bf16)v0.x; o0[1]=(bf16)v0.y; o0[2]=(bf16)v0.z; o0[3]=(bf16)v0.w;
        o0[4]=(bf16)v1.x; o0[5]=(bf16)v1.y; o0[6]=(bf16)v1.z; o0[7]=(bf16)v1.w;
        o1[0]=(bf16)v2.x; o1[1]=(bf16)v2.y; o1[2]=(bf16)v2.z; o1[3]=(bf16)v2.w;
        o1[4]=(bf16)v3.x; o1[5]=(bf16)v3.y; o1[6]=(bf16)v3.z; o1[7]=(bf16)v3.w;
        ((bf16x8*)Wb)[(f4 >> 1) + 0] = o0;
        ((bf16x8*)Wb)[(f4 >> 1) + 1] = o1;
        return;
    }

    __shared__ bf16x8 sxl[NN];   // 32 KB
    const int bb0 = blk * 8;

    const float w0 = cw[0], w1 = cw[1], w2 = cw[2], w3 = cw[3];
    const float w4 = cw[4], w5 = cw[5], w6 = cw[6], w7 = cw[7];
    const float bias = cb[0];

    const int4* adj4 = (const int4*)adj;
    int4 a[8];
#pragma unroll
    for (int j = 0; j < 8; ++j) a[j] = adj4[t * 8 + j];

    bf16 oA[8][4], oB[8][4];

#pragma unroll
    for (int pp = 0; pp < 2; ++pp) {
        if (pp) __syncthreads();   // protect pass-0 reads from restage
        const int rb = bb0 + pp * 4;
        const float4* x0 = (const float4*)(x     + (size_t)(rb + 0) * NN);
        const float4* x1 = (const float4*)(x     + (size_t)(rb + 1) * NN);
        const float4* x2 = (const float4*)(x     + (size_t)(rb + 2) * NN);
        const float4* x3 = (const float4*)(x     + (size_t)(rb + 3) * NN);
        const float4* l0 = (const float4*)(label + (size_t)(rb + 0) * NN);
        const float4* l1 = (const float4*)(label + (size_t)(rb + 1) * NN);
        const float4* l2 = (const float4*)(label + (size_t)(rb + 2) * NN);
        const float4* l3 = (const float4*)(label + (size_t)(rb + 3) * NN);
#pragma unroll
        for (int q = 0; q < 2; ++q) {
            int i = q * 256 + t;             // float4 index, 512 per row
            float4 xa = x0[i], xb = x1[i], xc = x2[i], xd = x3[i];
            float4 la = l0[i], lb = l1[i], lc = l2[i], ld = l3[i];
            int n0i = i * 4;
            int sx  = (i >> 1) & 7;          // == ((n0i+c)>>3)&7 for c=0..3
            bf16x8 e;
            e[0]=(bf16)xa.x; e[1]=(bf16)la.x; e[2]=(bf16)xb.x; e[3]=(bf16)lb.x;
            e[4]=(bf16)xc.x; e[5]=(bf16)lc.x; e[6]=(bf16)xd.x; e[7]=(bf16)ld.x;
            sxl[(n0i + 0) ^ sx] = e;
            e[0]=(bf16)xa.y; e[1]=(bf16)la.y; e[2]=(bf16)xb.y; e[3]=(bf16)lb.y;
            e[4]=(bf16)xc.y; e[5]=(bf16)lc.y; e[6]=(bf16)xd.y; e[7]=(bf16)ld.y;
            sxl[(n0i + 1) ^ sx] = e;
            e[0]=(bf16)xa.z; e[1]=(bf16)la.z; e[2]=(bf16)xb.z; e[3]=(bf16)lb.z;
            e[4]=(bf16)xc.z; e[5]=(bf16)lc.z; e[6]=(bf16)xd.z; e[7]=(bf16)ld.z;
            sxl[(n0i + 2) ^ sx] = e;
            e[0]=(bf16)xa.w; e[1]=(bf16)la.w; e[2]=(bf16)xb.w; e[3]=(bf16)lb.w;
            e[4]=(bf16)xc.w; e[5]=(bf16)lc.w; e[6]=(bf16)xd.w; e[7]=(bf16)ld.w;
            sxl[(n0i + 3) ^ sx] = e;
        }
        __syncthreads();

        bf16 (*od)[4] = pp ? oB : oA;
#pragma unroll
        for (int j = 0; j < 8; ++j) {
            int4 aa = a[j];
            bf16x8 p0 = sxl[aa.x ^ ((aa.x >> 3) & 7)];
            bf16x8 p1 = sxl[aa.y ^ ((aa.y >> 3) & 7)];
            bf16x8 p2 = sxl[aa.z ^ ((aa.z >> 3) & 7)];
            bf16x8 p3 = sxl[aa.w ^ ((aa.w >> 3) & 7)];
            float v0 = bias
                + w0*(float)p0[0] + w1*(float)p1[0] + w2*(float)p2[0] + w3*(float)p3[0]
                + w4*(float)p0[1] + w5*(float)p1[1] + w6*(float)p2[1] + w7*(float)p3[1];
            float v1 = bias
                + w0*(float)p0[2] + w1*(float)p1[2] + w2*(float)p2[2] + w3*(float)p3[2]
                + w4*(float)p0[3] + w5*(float)p1[3] + w6*(float)p2[3] + w7*(float)p3[3];
            float v2 = bias
                + w0*(float)p0[4] + w1*(float)p1[4] + w2*(float)p2[4] + w3*(float)p3[4]
                + w4*(float)p0[5] + w5*(float)p1[5] + w6*(float)p2[5] + w7*(float)p3[5];
            float v3 = bias
                + w0*(float)p0[6] + w1*(float)p1[6] + w2*(float)p2[6] + w3*(float)p3[6]
                + w4*(float)p0[7] + w5*(float)p1[7] + w6*(float)p2[7] + w7*(float)p3[7];
            od[j][0] = (bf16)fmaxf(v0, 0.0f);
            od[j][1] = (bf16)fmaxf(v1, 0.0f);
            od[j][2] = (bf16)fmaxf(v2, 0.0f);
            od[j][3] = (bf16)fmaxf(v3, 0.0f);
        }
    }

    bf16* vout = Vp + (size_t)blk * 16384 + t * 64;
#pragma unroll
    for (int j = 0; j < 8; ++j) {
        bf16x8 e;
        e[0] = oA[j][0]; e[1] = oA[j][1]; e[2] = oA[j][2]; e[3] = oA[j][3];
        e[4] = oB[j][0]; e[5] = oB[j][1]; e[6] = oB[j][2]; e[7] = oB[j][3];
        *(bf16x8*)(vout + j * 8) = e;
    }
}

// ---------------------------------------------------------------------------
// K3: out(8192x2048) = A * W^T + bias.  R3 schedule + ledger (unchanged).
// R9/R10: A-side chunk bijection redesigned with the OCTET constraint.
// Diagnosis (R7=R8=exactly 4194304 conflicts = +4 cyc on each of the 2^20
// A-reads): ds_read_b128 is conflict-free iff each 8-CONSECUTIVE-LANE octet
// covers all eight 16B slots distinctly. R3/R6's slot=(l16&7)^q does (zero
// conflicts); R7's slot=bq(l16) takes 4 values/octet; R8's ^l4 is constant
// within an octet -> identical count.
// Per-128-row-half mapping (mu = m-row in half, q = k-chunk in [0,8)):
//   chunk(mu,q) = q*128 + (mu>>3)*8 + ((mu&7)^q)        [bijective: inverse
//   q=c>>7, mu=((c>>3)&15)*8 + ((c&7)^q)]
// Read slot = (l16&7)^q -> bijection of lane&7 per octet (R3 class, zero).
// Stage decode (chunk c = j*512 + w*64 + lane):
//   q = j*4 + (w>>1)  [wave-uniform]; l3 = (lane&7)^q;
//   mu = (w&1)*64 + (lane>>3)*8 + l3
//   src = ((l3&3)*256 + kt/8 + q)*16384 + (rb/4 + mu>>2)*8
// Coalescing: per async16-wave the 64 lanes form 4 contiguous 256B runs
// (for each l3&3 value, mu>>2 sweeps 16 consecutive values). Verified
// round-trip: (j=1,w=2,lane=13) -> chunk 653 -> src elem 213008 on both
// the stage and read paths.
__global__ __launch_bounds__(512, 2) void gemm_bt(
    const bf16* __restrict__ A, const bf16* __restrict__ W,
    const float* __restrict__ bias, float* __restrict__ out) {
    __shared__ __attribute__((aligned(16))) bf16 sA[2][16384];
    __shared__ __attribute__((aligned(16))) bf16 sB[2][16384];

    const int t    = threadIdx.x;
    const int lane = t & 63;
    const int wv   = t >> 6;
    const int wm   = wv & 1;     // 2 M-waves
    const int wn   = wv >> 1;    // 4 N-waves
    const int l16  = lane & 15;
    const int l4   = lane >> 4;

    // Chunked XCD mapping: each XCD owns 4 bx (A panels) x all 8 by.
    const int xcd = blockIdx.x & 7;
    const int loc = blockIdx.x >> 3;        // [0,32)
    const int bx  = xcd * 4 + (loc >> 3);   // [0,32)
    const int by  = loc & 7;                // [0,8)
    const int m0  = bx * 256;
    const int n0  = by * 256;

    // B staging thread map (unchanged)
    const int r8  = t >> 3;
    const int c8  = ((t & 7) ^ (r8 & 7)) * 8;
    const int dst = t * 8;

    // A staging source bases per async j (octet-constrained bijection)
    int aBv[2];
#pragma unroll
    for (int j = 0; j < 2; ++j) {
        const int q   = j * 4 + (wv >> 1);
        const int l3  = (lane & 7) ^ q;
        const int mu2 = (wv & 1) * 16 + (lane >> 3) * 2 + (l3 >> 2); // mu>>2
        aBv[j] = ((l3 & 3) * 256 + q) * 16384 + mu2 * 8;
    }
    const int aBase0 = aBv[0], aBase1 = aBv[1];

    // A frag read offsets (elements): for ks, mf, mh:
    //   off = wm*8192 + (ks*4+l4)*1024 + mh*512 + mf*128
    //       + (l16>>3)*64 + ((l16&7)^(ks*4+l4))*8
    const int aX0 = wm * 8192 + l4 * 1024 + (l16 >> 3) * 64
                  + ((l16 & 7) ^ l4) * 8;
    const int aX1 = wm * 8192 + (4 + l4) * 1024 + (l16 >> 3) * 64
                  + ((l16 & 7) ^ (4 + l4)) * 8;

    // B frag read offsets (unchanged)
    const int sw    = l16 & 7;
    const int bOff0 = (wn * 64 + l16) * 64 + ((l4    ) ^ sw) * 8;
    const int bOff1 = (wn * 64 + l16) * 64 + ((l4 + 4) ^ sw) * 8;

    f32x4  acc[8][4] = {};
    bf16x8 aR[4][2], bR[4][2];

#define GBAR()  asm volatile("s_barrier" ::: "memory")
#define LGKM0() do { asm volatile("s_waitcnt lgkmcnt(0)" ::: "memory"); \
                     __builtin_amdgcn_sched_barrier(0); } while (0)
#define VMW6()  asm volatile("s_waitcnt vmcnt(6)" ::: "memory")
#define VMW0()  asm volatile("s_waitcnt vmcnt(0)" ::: "memory")

// B (W) staging: row-major [n][k] (unchanged)
#define STGW(rb, kt, lp) do {                                             \
        const bf16* _s = W + (size_t)((rb) + r8) * 2048 + (kt) + c8;      \
        async16(_s, (lp) + dst);                                          \
        async16(_s + (size_t)64 * 2048, (lp) + 4096 + dst);               \
    } while (0)

// A staging from V' via the octet-constrained bijection: 4x256B runs/wave.
#define STGA(rb, kt, lp) do {                                             \
        const size_t _o = (size_t)(kt) * 2048 + (rb) * 2;                 \
        async16(A + aBase0 + _o, (lp) + dst);                             \
        async16(A + aBase1 + _o, (lp) + 4096 + dst);                      \
    } while (0)

// A frag reads in the new layout
#define LDA(sp, mh) do {                                                  \
        const bf16* _p = (sp) + (mh) * 512;                               \
        aR[0][0] = *(const bf16x8*)(_p +   0 + aX0);                      \
        aR[0][1] = *(const bf16x8*)(_p +   0 + aX1);                      \
        aR[1][0] = *(const bf16x8*)(_p + 128 + aX0);                      \
        aR[1][1] = *(const bf16x8*)(_p + 128 + aX1);                      \
        aR[2][0] = *(const bf16x8*)(_p + 256 + aX0);                      \
        aR[2][1] = *(const bf16x8*)(_p + 256 + aX1);                      \
        aR[3][0] = *(const bf16x8*)(_p + 384 + aX0);                      \
        aR[3][1] = *(const bf16x8*)(_p + 384 + aX1);                      \
    } while (0)

#define LDB(sp, nh) do {                                                  \
        const bf16* _p = (sp) + (nh) * 2048;                              \
        bR[(nh)*2+0][0] = *(const bf16x8*)(_p + bOff0);                   \
        bR[(nh)*2+0][1] = *(const bf16x8*)(_p + bOff1);                   \
        bR[(nh)*2+1][0] = *(const bf16x8*)(_p + 1024 + bOff0);            \
        bR[(nh)*2+1][1] = *(const bf16x8*)(_p + 1024 + bOff1);            \
    } while (0)

#define MM(mh, nh) do {                                                   \
        __builtin_amdgcn_s_setprio(1);                                    \
        _Pragma("unroll")                                                 \
        for (int _ks = 0; _ks < 2; ++_ks)                                 \
            _Pragma("unroll")                                             \
            for (int _mf = 0; _mf < 4; ++_mf)                             \
                _Pragma("unroll")                                         \
                for (int _nf = 0; _nf < 2; ++_nf)                         \
                    acc[(mh)*4+_mf][(nh)*2+_nf] =                         \
                        __builtin_amdgcn_mfma_f32_16x16x32_bf16(          \
                            aR[_mf][_ks], bR[(nh)*2+_nf][_ks],            \
                            acc[(mh)*4+_mf][(nh)*2+_nf], 0, 0, 0);        \
        __builtin_amdgcn_s_setprio(0);                                    \
    } while (0)

    bf16* const sA0 = &sA[0][0]; bf16* const sA1 = &sA[1][0];
    bf16* const sB0 = &sB[0][0]; bf16* const sB1 = &sB[1][0];

    // prologue: A(0),B(0) (8 ops) + B(1),A(1).h0 (6 ops) = 14; vmcnt(6)
    // retires the 8 oldest = all of tile 0, leaving invariant
    // {B(1).h0, B(1).h1, A(1).h0}.
    STGA(m0,       0,  sA0);
    STGA(m0 + 128, 0,  sA0 + 8192);
    STGW(n0,       0,  sB0);
    STGW(n0 + 128, 0,  sB0 + 8192);
    STGW(n0,       64, sB1);
    STGW(n0 + 128, 64, sB1 + 8192);
    STGA(m0,       64, sA1);
    VMW6();
    GBAR();

    for (int i = 0; i < 15; ++i) {
        const int kb = i * 128;
        // ph1: stage A(2i+1).h1
        LDA(sA0, 0); LDB(sB0, 0);
        STGA(m0 + 128, kb + 64, sA1 + 8192);
        GBAR(); LGKM0();
        MM(0, 0);
        GBAR();
        // ph2
        LDB(sB0, 1);
        GBAR(); LGKM0();
        MM(0, 1);
        GBAR();
        // ph3: stage B(2i+2).h0
        LDA(sA0, 1);
        STGW(n0, kb + 128, sB0);
        GBAR(); LGKM0();
        MM(1, 0);
        GBAR();
        // ph4: stage B(2i+2).h1 + A(2i+2).h0; wait buf1
        STGW(n0 + 128, kb + 128, sB0 + 8192);
        STGA(m0,       kb + 128, sA0);
        GBAR(); LGKM0();
        MM(1, 1);
        VMW6();
        GBAR();
        // ph5: stage A(2i+2).h1
        LDA(sA1, 0); LDB(sB1, 0);
        STGA(m0 + 128, kb + 128, sA0 + 8192);
        GBAR(); LGKM0();
        MM(0, 0);
        GBAR();
        // ph6
        LDB(sB1, 1);
        GBAR(); LGKM0();
        MM(0, 1);
        GBAR();
        // ph7: stage B(2i+3).h0
        LDA(sA1, 1);
        STGW(n0, kb + 192, sB1);
        GBAR(); LGKM0();
        MM(1, 0);
        GBAR();
        // ph8: stage B(2i+3).h1 + A(2i+3).h0; wait buf0
        STGW(n0 + 128, kb + 192, sB1 + 8192);
        STGA(m0,       kb + 192, sA1);
        GBAR(); LGKM0();
        MM(1, 1);
        VMW6();
        GBAR();
    }

    // tail: tiles 30 (buf0), 31 (buf1); only A(31).h1 remains to stage
    LDA(sA0, 0); LDB(sB0, 0);
    STGA(m0 + 128, 1984, sA1 + 8192);
    GBAR(); LGKM0(); MM(0, 0); GBAR();
    LDB(sB0, 1);
    GBAR(); LGKM0(); MM(0, 1); GBAR();
    LDA(sA0, 1);
    GBAR(); LGKM0(); MM(1, 0); GBAR();
    GBAR(); LGKM0(); MM(1, 1);
    VMW0();                      // drain tile 31
    GBAR();
    LDA(sA1, 0); LDB(sB1, 0);
    GBAR(); LGKM0(); MM(0, 0); GBAR();
    LDB(sB1, 1);
    GBAR(); LGKM0(); MM(0, 1); GBAR();
    LDA(sA1, 1);
    GBAR(); LGKM0(); MM(1, 0); GBAR();
    GBAR(); LGKM0(); MM(1, 1);

    // epilogue: bias + store (regs only)
#pragma unroll
    for (int nf = 0; nf < 4; ++nf) {
        const int col = n0 + wn * 64 + nf * 16 + l16;
        const float bc = bias[col];
#pragma unroll
        for (int mf = 0; mf < 8; ++mf) {
            const size_t row = (size_t)(m0 + wm * 128 + mf * 16 + l4 * 4);
#pragma unroll
            for (int rr = 0; rr < 4; ++rr)
                out[(row + rr) * 2048 + col] = acc[mf][nf][rr] + bc;
        }
    }
#undef STGW
#undef STGA
#undef LDA
#undef LDB
#undef MM
#undef GBAR
#undef LGKM0
#undef VMW6
#undef VMW0
}

// ---------------------------------------------------------------------------
extern "C" void kernel_launch(void* const* d_in, const int* in_sizes, int n_in,
                              void* d_out, int out_size, void* d_ws, size_t ws_size,
                              hipStream_t stream) {
    (void)in_sizes; (void)n_in; (void)out_size; (void)ws_size;
    const float* x     = (const float*)d_in[0];
    const float* label = (const float*)d_in[1];
    const int*   adj   = (const int*)d_in[2];
    const float* cw    = (const float*)d_in[3];
    const float* cb    = (const float*)d_in[4];
    const float* lw    = (const float*)d_in[5];
    const float* lb    = (const float*)d_in[6];
    float* out = (float*)d_out;

    // scratch: V' (33.5 MB) at ws, Wb at ws+33.5MB.
    bf16* Vp = (bf16*)d_ws;
    bf16* Wb = (bf16*)((char*)d_ws + (size_t)2048 * 8192 * 2);

    conv_gather_t<<<2048, 256, 0, stream>>>(x, label, adj, cw, cb, Vp, lw, Wb);
    gemm_bt<<<dim3(256), 512, 0, stream>>>(Vp, Wb, lb, out);
}